// Round 2
// baseline (944.266 us; speedup 1.0000x reference)
//
#include <hip/hip_runtime.h>
#include <stdint.h>

#define NN 100000
#define NE 1600000
#define FIN 602
#define KP1 608      // 19 * 32, zero-padded K for layer-1 GEMM
#define H 256
#define C 42
#define NP2 48       // padded N for layer-2 GEMM (3 tiles of 16)
#define NB1 98       // ceil(NN / 1024) scan blocks

typedef __bf16 bf16;
typedef __bf16 bf16x8 __attribute__((ext_vector_type(8)));
typedef float f32x4 __attribute__((ext_vector_type(4)));

__device__ __forceinline__ float b2f(bf16 v) { return (float)v; }
__device__ __forceinline__ bf16 f2b(float v) { return (bf16)v; }
__device__ __forceinline__ float us2f(unsigned short u) {
    union { unsigned int i; float f; } w; w.i = ((unsigned int)u) << 16; return w.f;
}

// ---------------- CSR build ----------------

__global__ void k_zero(int* __restrict__ p, int n) {
    int i = blockIdx.x * 256 + threadIdx.x;
    if (i < n) p[i] = 0;
}

__global__ void k_count(const int* __restrict__ dst, int* __restrict__ cnt) {
    int e = blockIdx.x * 256 + threadIdx.x;
    if (e < NE) atomicAdd(&cnt[dst[e]], 1);
}

__global__ void k_dinv(const int* __restrict__ cnt, float* __restrict__ dinv) {
    int i = blockIdx.x * 256 + threadIdx.x;
    if (i < NN) dinv[i] = rsqrtf((float)(cnt[i] + 1));  // +1 self loop
}

__global__ __launch_bounds__(256) void k_scan1(const int* __restrict__ cnt,
                                               int* __restrict__ excl, int* __restrict__ bsum) {
    __shared__ int ts[256];
    const int tid = threadIdx.x;
    const int base = blockIdx.x * 1024 + tid * 4;
    int v[4];
#pragma unroll
    for (int j = 0; j < 4; ++j) v[j] = (base + j < NN) ? cnt[base + j] : 0;
    int s = v[0] + v[1] + v[2] + v[3];
    ts[tid] = s;
    __syncthreads();
    for (int off = 1; off < 256; off <<= 1) {
        int t = (tid >= off) ? ts[tid - off] : 0;
        __syncthreads();
        if (tid >= off) ts[tid] += t;
        __syncthreads();
    }
    int prefix = ts[tid] - s;
    if (tid == 255) bsum[blockIdx.x] = ts[255];
    int run = prefix;
#pragma unroll
    for (int j = 0; j < 4; ++j) {
        if (base + j < NN) excl[base + j] = run;
        run += v[j];
    }
}

__global__ __launch_bounds__(128) void k_scan2(int* __restrict__ bsum) {
    __shared__ int ts[128];
    const int tid = threadIdx.x;
    int v = (tid < NB1) ? bsum[tid] : 0;
    ts[tid] = v;
    __syncthreads();
    for (int off = 1; off < 128; off <<= 1) {
        int t = (tid >= off) ? ts[tid - off] : 0;
        __syncthreads();
        if (tid >= off) ts[tid] += t;
        __syncthreads();
    }
    if (tid < NB1) bsum[tid] = ts[tid] - v;
}

__global__ __launch_bounds__(256) void k_scan3(const int* __restrict__ excl, const int* __restrict__ bsum,
                                               int* __restrict__ rowptr, int* __restrict__ cursor) {
    const int tid = threadIdx.x;
    const int base = blockIdx.x * 1024 + tid * 4;
    const int add = bsum[blockIdx.x];
#pragma unroll
    for (int j = 0; j < 4; ++j) {
        int i = base + j;
        if (i < NN) { int r = excl[i] + add; rowptr[i] = r; cursor[i] = r; }
    }
    if (blockIdx.x == 0 && tid == 0) rowptr[NN] = NE;
}

__global__ void k_fill(const int* __restrict__ src, const int* __restrict__ dst,
                       int* __restrict__ cursor, int* __restrict__ esrc) {
    int e = blockIdx.x * 256 + threadIdx.x;
    if (e < NE) {
        int d = dst[e];
        int pos = atomicAdd(&cursor[d], 1);
        esrc[pos] = src[e];
    }
}

// ---------------- weight transposes + fp32->bf16 convert ----------------

__global__ void k_transpose_w1(const float* __restrict__ w1, bf16* __restrict__ w1t) {
    int idx = blockIdx.x * 256 + threadIdx.x;  // grid covers 256*608 exactly
    int n = idx / KP1;
    int k = idx % KP1;
    w1t[idx] = (k < FIN) ? f2b(w1[(size_t)k * H + n]) : (bf16)0.0f;
}

__global__ void k_transpose_w2(const float* __restrict__ w2, bf16* __restrict__ w2t) {
    int idx = blockIdx.x * 256 + threadIdx.x;  // grid covers 48*256 exactly
    int n = idx >> 8;
    int k = idx & 255;
    w2t[idx] = (n < C) ? f2b(w2[(size_t)k * C + n]) : (bf16)0.0f;
}

// ---------------- GEMM1: h1[NN][256] = bf16(x)[NN][602] @ bf16(W1) ----------------
// Barrier-free direct-load design. Post-mortem of the LDS-staged versions showed
// a 4-wave barrier convoy at ~2 blocks/CU: ~3000 cyc/block-step vs ~80 cyc MFMA,
// and register prefetch across the barriers bought nothing. Here: NO LDS, NO
// barriers. Each wave loads its own A fragments directly (the 4x duplication
// across waves is same-CU, L1/L2-hit); the compiler software-pipelines loads
// across K-steps (unroll 2) since nothing blocks reordering. Tile 64x128,
// grid 2x1563; wave = 4 row-tiles x 2 col-tiles -> 32 AGPR acc (half of before)
// for higher occupancy. Last K-step peeled (cols 576..607, only 602 valid).
// A-frag: lane(q=lane>>4, r=lane&15) holds A[m=r][k=q*8+j]; C/D: col=r, row=q*4+reg.

__global__ __launch_bounds__(256) void k_gemm1(const float* __restrict__ x,
                                               const bf16* __restrict__ w1t,
                                               bf16* __restrict__ h1) {
    const int tid = threadIdx.x;
    const int wave = tid >> 6;
    const int lane = tid & 63;
    const int q = lane >> 4;
    const int r = lane & 15;
    const int b = blockIdx.x;
    const int row0 = (b >> 1) * 64;          // col-half pairs adjacent in dispatch
    const int col0 = (b & 1) * 128 + wave * 32;

    const float* arow[4];
#pragma unroll
    for (int rt = 0; rt < 4; ++rt) {
        int m = row0 + rt * 16 + r;
        if (m >= NN) m = NN - 1;             // clamp; stores guarded
        arow[rt] = x + (size_t)m * FIN + q * 8;
    }
    const bf16* brow[2];
#pragma unroll
    for (int ct = 0; ct < 2; ++ct)
        brow[ct] = w1t + (size_t)(col0 + ct * 16 + r) * KP1 + q * 8;

    f32x4 acc[4][2];
#pragma unroll
    for (int a = 0; a < 4; ++a)
#pragma unroll
        for (int c = 0; c < 2; ++c) acc[a][c] = (f32x4){0.f, 0.f, 0.f, 0.f};

#pragma unroll 2
    for (int kk = 0; kk < 18; ++kk) {
        const int k0 = kk * 32;
        bf16x8 af[4];
#pragma unroll
        for (int rt = 0; rt < 4; ++rt) {
            // x rows are only 8B-aligned (602 floats = 2408 B stride) -> float2
            const float2* p = (const float2*)(arow[rt] + k0);
            float2 f0 = p[0], f1 = p[1], f2 = p[2], f3 = p[3];
            union { bf16 s[8]; bf16x8 v; } pk;
            pk.s[0] = f2b(f0.x); pk.s[1] = f2b(f0.y);
            pk.s[2] = f2b(f1.x); pk.s[3] = f2b(f1.y);
            pk.s[4] = f2b(f2.x); pk.s[5] = f2b(f2.y);
            pk.s[6] = f2b(f3.x); pk.s[7] = f2b(f3.y);
            af[rt] = pk.v;
        }
#pragma unroll
        for (int ct = 0; ct < 2; ++ct) {
            union { uint4 u; bf16x8 v; } ub;
            ub.u = *(const uint4*)(brow[ct] + k0);
#pragma unroll
            for (int rt = 0; rt < 4; ++rt)
                acc[rt][ct] = __builtin_amdgcn_mfma_f32_16x16x32_bf16(af[rt], ub.v, acc[rt][ct], 0, 0, 0);
        }
    }

    // peeled last K-step: cols 576..607, valid < 602. q==3 covers 600..607 -> 2 valid.
    {
        const int k0 = 576;
        bf16x8 af[4];
#pragma unroll
        for (int rt = 0; rt < 4; ++rt) {
            union { bf16 s[8]; bf16x8 v; } pk;
            if (q < 3) {
                const float2* p = (const float2*)(arow[rt] + k0);
                float2 f0 = p[0], f1 = p[1], f2 = p[2], f3 = p[3];
                pk.s[0] = f2b(f0.x); pk.s[1] = f2b(f0.y);
                pk.s[2] = f2b(f1.x); pk.s[3] = f2b(f1.y);
                pk.s[4] = f2b(f2.x); pk.s[5] = f2b(f2.y);
                pk.s[6] = f2b(f3.x); pk.s[7] = f2b(f3.y);
            } else {
                const float* p = arow[rt] + k0;   // cols 600, 601
                pk.s[0] = f2b(p[0]); pk.s[1] = f2b(p[1]);
#pragma unroll
                for (int j = 2; j < 8; ++j) pk.s[j] = (bf16)0.0f;
            }
            af[rt] = pk.v;
        }
#pragma unroll
        for (int ct = 0; ct < 2; ++ct) {
            union { uint4 u; bf16x8 v; } ub;
            ub.u = *(const uint4*)(brow[ct] + k0);  // w1t zero-padded past 602
#pragma unroll
            for (int rt = 0; rt < 4; ++rt)
                acc[rt][ct] = __builtin_amdgcn_mfma_f32_16x16x32_bf16(af[rt], ub.v, acc[rt][ct], 0, 0, 0);
        }
    }

#pragma unroll
    for (int rt = 0; rt < 4; ++rt) {
#pragma unroll
        for (int ct = 0; ct < 2; ++ct) {
            const int col = col0 + ct * 16 + r;
#pragma unroll
            for (int rr = 0; rr < 4; ++rr) {
                const int m = row0 + rt * 16 + q * 4 + rr;
                if (m < NN) h1[(size_t)m * H + col] = f2b(acc[rt][ct][rr]);
            }
        }
    }
}

// ---------------- layer-1 pull aggregation + bias + relu (fused) ----------------

__global__ __launch_bounds__(64) void k_gather1(const int* __restrict__ rowptr,
                                                const int* __restrict__ esrc,
                                                const bf16* __restrict__ h1,
                                                const float* __restrict__ dinv,
                                                const float* __restrict__ b1,
                                                bf16* __restrict__ hb) {
    const int n = blockIdx.x;
    const int tid = threadIdx.x;
    const float dn = dinv[n];

    uint2 u = ((const uint2*)(h1 + (size_t)n * H))[tid];
    float ws = dn * dn;
    float a0 = us2f((unsigned short)(u.x & 0xffff)) * ws;
    float a1 = us2f((unsigned short)(u.x >> 16)) * ws;
    float a2 = us2f((unsigned short)(u.y & 0xffff)) * ws;
    float a3 = us2f((unsigned short)(u.y >> 16)) * ws;

    const int beg = rowptr[n], end = rowptr[n + 1];
    int j = beg;
    // unroll-by-4: 4 independent load chains in flight
    for (; j + 3 < end; j += 4) {
        int s0 = esrc[j], s1 = esrc[j + 1], s2 = esrc[j + 2], s3 = esrc[j + 3];
        float w0 = dinv[s0] * dn, w1 = dinv[s1] * dn, w2 = dinv[s2] * dn, w3 = dinv[s3] * dn;
        uint2 v0 = ((const uint2*)(h1 + (size_t)s0 * H))[tid];
        uint2 v1 = ((const uint2*)(h1 + (size_t)s1 * H))[tid];
        uint2 v2 = ((const uint2*)(h1 + (size_t)s2 * H))[tid];
        uint2 v3 = ((const uint2*)(h1 + (size_t)s3 * H))[tid];
        a0 += us2f((unsigned short)(v0.x & 0xffff)) * w0;
        a1 += us2f((unsigned short)(v0.x >> 16)) * w0;
        a2 += us2f((unsigned short)(v0.y & 0xffff)) * w0;
        a3 += us2f((unsigned short)(v0.y >> 16)) * w0;
        a0 += us2f((unsigned short)(v1.x & 0xffff)) * w1;
        a1 += us2f((unsigned short)(v1.x >> 16)) * w1;
        a2 += us2f((unsigned short)(v1.y & 0xffff)) * w1;
        a3 += us2f((unsigned short)(v1.y >> 16)) * w1;
        a0 += us2f((unsigned short)(v2.x & 0xffff)) * w2;
        a1 += us2f((unsigned short)(v2.x >> 16)) * w2;
        a2 += us2f((unsigned short)(v2.y & 0xffff)) * w2;
        a3 += us2f((unsigned short)(v2.y >> 16)) * w2;
        a0 += us2f((unsigned short)(v3.x & 0xffff)) * w3;
        a1 += us2f((unsigned short)(v3.x >> 16)) * w3;
        a2 += us2f((unsigned short)(v3.y & 0xffff)) * w3;
        a3 += us2f((unsigned short)(v3.y >> 16)) * w3;
    }
    for (; j < end; ++j) {
        int s = esrc[j];
        float w = dinv[s] * dn;
        uint2 v = ((const uint2*)(h1 + (size_t)s * H))[tid];
        a0 += us2f((unsigned short)(v.x & 0xffff)) * w;
        a1 += us2f((unsigned short)(v.x >> 16)) * w;
        a2 += us2f((unsigned short)(v.y & 0xffff)) * w;
        a3 += us2f((unsigned short)(v.y >> 16)) * w;
    }

    float4 bb = ((const float4*)b1)[tid];
    a0 += bb.x; a1 += bb.y; a2 += bb.z; a3 += bb.w;
    a0 = a0 > 0.f ? a0 : 0.f;
    a1 = a1 > 0.f ? a1 : 0.f;
    a2 = a2 > 0.f ? a2 : 0.f;
    a3 = a3 > 0.f ? a3 : 0.f;

    union { unsigned short s[4]; uint2 u; } pk;
    union { bf16 b; unsigned short s; } cv;
    cv.b = f2b(a0); pk.s[0] = cv.s;
    cv.b = f2b(a1); pk.s[1] = cv.s;
    cv.b = f2b(a2); pk.s[2] = cv.s;
    cv.b = f2b(a3); pk.s[3] = cv.s;
    ((uint2*)(hb + (size_t)n * H))[tid] = pk.u;
}

// ---------------- GEMM2: h2[NN][42] = hb[NN][256] @ W2 ----------------
// Same barrier-free direct-load design. Waves own disjoint 32-row slabs, so
// direct A loads have ZERO cross-wave duplication; B (24.6 KB) is L2-hot.

__global__ __launch_bounds__(256) void k_gemm2(const bf16* __restrict__ hb,
                                               const bf16* __restrict__ w2t,
                                               bf16* __restrict__ h2) {
    const int tid = threadIdx.x;
    const int wave = tid >> 6;
    const int lane = tid & 63;
    const int q = lane >> 4;
    const int r = lane & 15;
    const int row0 = blockIdx.x * 128 + wave * 32;

    const bf16* arow[2];
#pragma unroll
    for (int rt = 0; rt < 2; ++rt) {
        int m = row0 + rt * 16 + r;
        if (m >= NN) m = NN - 1;
        arow[rt] = hb + (size_t)m * H + q * 8;
    }
    const bf16* brow[3];
#pragma unroll
    for (int ct = 0; ct < 3; ++ct)
        brow[ct] = w2t + (size_t)(ct * 16 + r) * H + q * 8;

    f32x4 acc[2][3];
#pragma unroll
    for (int a = 0; a < 2; ++a)
#pragma unroll
        for (int c = 0; c < 3; ++c) acc[a][c] = (f32x4){0.f, 0.f, 0.f, 0.f};

#pragma unroll 2
    for (int kk = 0; kk < 8; ++kk) {
        const int k0 = kk * 32;
        bf16x8 af[2];
#pragma unroll
        for (int rt = 0; rt < 2; ++rt) {
            union { uint4 u; bf16x8 v; } ua;
            ua.u = *(const uint4*)(arow[rt] + k0);
            af[rt] = ua.v;
        }
#pragma unroll
        for (int ct = 0; ct < 3; ++ct) {
            union { uint4 u; bf16x8 v; } ub;
            ub.u = *(const uint4*)(brow[ct] + k0);
#pragma unroll
            for (int rt = 0; rt < 2; ++rt)
                acc[rt][ct] = __builtin_amdgcn_mfma_f32_16x16x32_bf16(af[rt], ub.v, acc[rt][ct], 0, 0, 0);
        }
    }

#pragma unroll
    for (int rt = 0; rt < 2; ++rt) {
#pragma unroll
        for (int ct = 0; ct < 3; ++ct) {
            const int col = ct * 16 + r;
            if (col < C) {
#pragma unroll
                for (int rr = 0; rr < 4; ++rr) {
                    const int m = row0 + rt * 16 + q * 4 + rr;
                    if (m < NN) h2[(size_t)m * C + col] = f2b(acc[rt][ct][rr]);
                }
            }
        }
    }
}

// ---------------- layer-2 pull aggregation + bias + log_softmax (fused) ----------------

__global__ __launch_bounds__(64) void k_gather2(const int* __restrict__ rowptr,
                                                const int* __restrict__ esrc,
                                                const bf16* __restrict__ h2,
                                                const float* __restrict__ dinv,
                                                const float* __restrict__ b2,
                                                float* __restrict__ out) {
    const int n = blockIdx.x;
    const int c = threadIdx.x;
    const float dn = dinv[n];

    float acc = 0.f;
    if (c < C) acc = b2f(h2[(size_t)n * C + c]) * dn * dn;

    const int beg = rowptr[n], end = rowptr[n + 1];
    int j = beg;
    for (; j + 3 < end; j += 4) {
        int s0 = esrc[j], s1 = esrc[j + 1], s2 = esrc[j + 2], s3 = esrc[j + 3];
        float w0 = dinv[s0] * dn, w1 = dinv[s1] * dn, w2 = dinv[s2] * dn, w3 = dinv[s3] * dn;
        if (c < C) {
            float v0 = b2f(h2[(size_t)s0 * C + c]);
            float v1 = b2f(h2[(size_t)s1 * C + c]);
            float v2 = b2f(h2[(size_t)s2 * C + c]);
            float v3 = b2f(h2[(size_t)s3 * C + c]);
            acc += v0 * w0 + v1 * w1 + v2 * w2 + v3 * w3;
        }
    }
    for (; j < end; ++j) {
        int s = esrc[j];
        float w = dinv[s] * dn;
        if (c < C) acc += b2f(h2[(size_t)s * C + c]) * w;
    }

    float v = (c < C) ? acc + b2[c] : -INFINITY;
    float m = v;
#pragma unroll
    for (int o = 32; o > 0; o >>= 1) m = fmaxf(m, __shfl_xor(m, o, 64));
    float ex = (c < C) ? expf(v - m) : 0.f;
    float s = ex;
#pragma unroll
    for (int o = 32; o > 0; o >>= 1) s += __shfl_xor(s, o, 64);
    if (c < C) out[(size_t)n * C + c] = (v - m) - logf(s);
}

// ---------------- launch ----------------

extern "C" void kernel_launch(void* const* d_in, const int* in_sizes, int n_in,
                              void* d_out, int out_size, void* d_ws, size_t ws_size,
                              hipStream_t stream) {
    const float* x  = (const float*)d_in[0];  // fp32 [NN][602]
    const int*   ei = (const int*)d_in[1];    // int32 [2][NE]
    const float* w1 = (const float*)d_in[2];  // fp32 [602][256]
    const float* b1 = (const float*)d_in[3];  // fp32 [256]
    const float* w2 = (const float*)d_in[4];  // fp32 [256][42]
    const float* b2 = (const float*)d_in[5];  // fp32 [42]
    float* out = (float*)d_out;               // fp32 [NN][42]

    const int* src = ei;
    const int* dst = ei + NE;

    char* base = (char*)d_ws;
    size_t off = 0;
    auto alloc = [&](size_t bytes) -> void* {
        void* p = base + off;
        off += (bytes + 255) & ~(size_t)255;
        return p;
    };
    int*   cnt    = (int*)alloc((size_t)NN * 4);
    float* dinv   = (float*)alloc((size_t)NN * 4);
    int*   excl   = (int*)alloc((size_t)NN * 4);
    int*   bsum   = (int*)alloc(128 * 4);
    int*   rowptr = (int*)alloc((size_t)(NN + 1) * 4);
    int*   cursor = (int*)alloc((size_t)NN * 4);
    int*   esrc   = (int*)alloc((size_t)NE * 4);
    bf16*  w1t    = (bf16*)alloc((size_t)H * KP1 * 2);
    bf16*  w2t    = (bf16*)alloc((size_t)NP2 * H * 2);
    bf16*  h1     = (bf16*)alloc((size_t)NN * H * 2);
    bf16*  hb     = (bf16*)alloc((size_t)NN * H * 2);
    bf16*  h2     = (bf16*)alloc((size_t)NN * C * 2);
    (void)ws_size;

    // CSR build + norm
    k_zero<<<dim3((NN + 255) / 256), dim3(256), 0, stream>>>(cnt, NN);
    k_count<<<dim3((NE + 255) / 256), dim3(256), 0, stream>>>(dst, cnt);
    k_dinv<<<dim3((NN + 255) / 256), dim3(256), 0, stream>>>(cnt, dinv);
    k_scan1<<<dim3(NB1), dim3(256), 0, stream>>>(cnt, excl, bsum);
    k_scan2<<<dim3(1), dim3(128), 0, stream>>>(bsum);
    k_scan3<<<dim3(NB1), dim3(256), 0, stream>>>(excl, bsum, rowptr, cursor);
    k_fill<<<dim3((NE + 255) / 256), dim3(256), 0, stream>>>(src, dst, cursor, esrc);

    // weights
    k_transpose_w1<<<dim3(KP1), dim3(256), 0, stream>>>(w1, w1t);
    k_transpose_w2<<<dim3(NP2), dim3(256), 0, stream>>>(w2, w2t);

    // layer 1 (gemm1 grid: 2 col-halves x 1563 row-blocks, interleaved)
    k_gemm1<<<dim3(2 * ((NN + 63) / 64)), dim3(256), 0, stream>>>(x, w1t, h1);
    k_gather1<<<dim3(NN), dim3(64), 0, stream>>>(rowptr, esrc, h1, dinv, b1, hb);

    // layer 2
    k_gemm2<<<dim3((NN + 127) / 128), dim3(256), 0, stream>>>(hb, w2t, h2);
    k_gather2<<<dim3(NN), dim3(64), 0, stream>>>(rowptr, esrc, h2, dinv, b2, out);
}

// Round 4
// 830.478 us; speedup vs baseline: 1.1370x; 1.1370x over previous
//
#include <hip/hip_runtime.h>
#include <stdint.h>

#define NN 100000
#define NE 1600000
#define FIN 602
#define KP1 608      // 19 * 32, zero-padded K for layer-1 GEMM
#define H 256
#define C 42
#define NP2 48       // padded N for layer-2 GEMM (3 tiles of 16)
#define NB1 98       // ceil(NN / 1024) scan blocks
#define KBLK 32      // gemm1 K-step
#define NCH (NN * 76)  // convert chunks: 76 x 8 cols per row (608)

typedef __bf16 bf16;
typedef __bf16 bf16x8 __attribute__((ext_vector_type(8)));
typedef float f32x4 __attribute__((ext_vector_type(4)));

__device__ __forceinline__ float b2f(bf16 v) { return (float)v; }
__device__ __forceinline__ bf16 f2b(float v) { return (bf16)v; }
__device__ __forceinline__ float us2f(unsigned short u) {
    union { unsigned int i; float f; } w; w.i = ((unsigned int)u) << 16; return w.f;
}

// ---------------- CSR build ----------------

__global__ void k_zero(int* __restrict__ p, int n) {
    int i = blockIdx.x * 256 + threadIdx.x;
    if (i < n) p[i] = 0;
}

__global__ void k_count(const int* __restrict__ dst, int* __restrict__ cnt) {
    int e = blockIdx.x * 256 + threadIdx.x;
    if (e < NE) atomicAdd(&cnt[dst[e]], 1);
}

__global__ void k_dinv(const int* __restrict__ cnt, float* __restrict__ dinv) {
    int i = blockIdx.x * 256 + threadIdx.x;
    if (i < NN) dinv[i] = rsqrtf((float)(cnt[i] + 1));  // +1 self loop
}

__global__ __launch_bounds__(256) void k_scan1(const int* __restrict__ cnt,
                                               int* __restrict__ excl, int* __restrict__ bsum) {
    __shared__ int ts[256];
    const int tid = threadIdx.x;
    const int base = blockIdx.x * 1024 + tid * 4;
    int v[4];
#pragma unroll
    for (int j = 0; j < 4; ++j) v[j] = (base + j < NN) ? cnt[base + j] : 0;
    int s = v[0] + v[1] + v[2] + v[3];
    ts[tid] = s;
    __syncthreads();
    for (int off = 1; off < 256; off <<= 1) {
        int t = (tid >= off) ? ts[tid - off] : 0;
        __syncthreads();
        if (tid >= off) ts[tid] += t;
        __syncthreads();
    }
    int prefix = ts[tid] - s;
    if (tid == 255) bsum[blockIdx.x] = ts[255];
    int run = prefix;
#pragma unroll
    for (int j = 0; j < 4; ++j) {
        if (base + j < NN) excl[base + j] = run;
        run += v[j];
    }
}

__global__ __launch_bounds__(128) void k_scan2(int* __restrict__ bsum) {
    __shared__ int ts[128];
    const int tid = threadIdx.x;
    int v = (tid < NB1) ? bsum[tid] : 0;
    ts[tid] = v;
    __syncthreads();
    for (int off = 1; off < 128; off <<= 1) {
        int t = (tid >= off) ? ts[tid - off] : 0;
        __syncthreads();
        if (tid >= off) ts[tid] += t;
        __syncthreads();
    }
    if (tid < NB1) bsum[tid] = ts[tid] - v;
}

__global__ __launch_bounds__(256) void k_scan3(const int* __restrict__ excl, const int* __restrict__ bsum,
                                               int* __restrict__ rowptr, int* __restrict__ cursor) {
    const int tid = threadIdx.x;
    const int base = blockIdx.x * 1024 + tid * 4;
    const int add = bsum[blockIdx.x];
#pragma unroll
    for (int j = 0; j < 4; ++j) {
        int i = base + j;
        if (i < NN) { int r = excl[i] + add; rowptr[i] = r; cursor[i] = r; }
    }
    if (blockIdx.x == 0 && tid == 0) rowptr[NN] = NE;
}

__global__ void k_fill(const int* __restrict__ src, const int* __restrict__ dst,
                       int* __restrict__ cursor, int* __restrict__ esrc) {
    int e = blockIdx.x * 256 + threadIdx.x;
    if (e < NE) {
        int d = dst[e];
        int pos = atomicAdd(&cursor[d], 1);
        esrc[pos] = src[e];
    }
}

// ---------------- weight transposes + fp32->bf16 convert ----------------

__global__ void k_transpose_w1(const float* __restrict__ w1, bf16* __restrict__ w1t) {
    int idx = blockIdx.x * 256 + threadIdx.x;  // grid covers 256*608 exactly
    int n = idx / KP1;
    int k = idx % KP1;
    w1t[idx] = (k < FIN) ? f2b(w1[(size_t)k * H + n]) : (bf16)0.0f;
}

__global__ void k_transpose_w2(const float* __restrict__ w2, bf16* __restrict__ w2t) {
    int idx = blockIdx.x * 256 + threadIdx.x;  // grid covers 48*256 exactly
    int n = idx >> 8;
    int k = idx & 255;
    w2t[idx] = (n < C) ? f2b(w2[(size_t)k * C + n]) : (bf16)0.0f;
}

// ---------------- x fp32 -> bf16 streaming convert (zero-padded to KP1) ----------------

__global__ __launch_bounds__(256) void k_convert(const float* __restrict__ x,
                                                 bf16* __restrict__ xb) {
    int idx = blockIdx.x * 256 + threadIdx.x;
    if (idx >= NCH) return;
    int n = idx / 76;
    int rem = idx - n * 76;
    int c0 = rem * 8;
    const float* p = x + (size_t)n * FIN + c0;
    union { bf16 s[8]; uint4 u; } pk;
    if (c0 + 8 <= FIN) {
        float2 f0 = ((const float2*)p)[0];
        float2 f1 = ((const float2*)p)[1];
        float2 f2v = ((const float2*)p)[2];
        float2 f3 = ((const float2*)p)[3];
        pk.s[0] = f2b(f0.x);  pk.s[1] = f2b(f0.y);
        pk.s[2] = f2b(f1.x);  pk.s[3] = f2b(f1.y);
        pk.s[4] = f2b(f2v.x); pk.s[5] = f2b(f2v.y);
        pk.s[6] = f2b(f3.x);  pk.s[7] = f2b(f3.y);
    } else {
#pragma unroll
        for (int j = 0; j < 8; ++j)
            pk.s[j] = (c0 + j < FIN) ? f2b(p[j]) : (bf16)0.0f;
    }
    *(uint4*)(xb + (size_t)n * KP1 + c0) = pk.u;
}

// ---------------- GEMM1: h1[NN][256] = xb[NN][608] @ bf16(W1) ----------------
// global_load_lds DMA pipeline (T3/T4 minimum template):
//   - BM=128 x BN=256 per block, 8 waves (512 thr), wave = 64 rows x 64 cols.
//   - A staged via 1x global_load_lds dwordx4 per thread (8 KB tile), 3
//     rotating LDS buffers, prefetch depth 2 (R2 post-mortem: ~1 TB/s plateau
//     came from ~3 KB outstanding per CU; this gets ~16-24 KB).
//   - counted s_waitcnt vmcnt(1) at phase end; B loads issued FIRST each phase
//     so the compiler's B-use wait retires stage(k+1) (FIFO) and keeps
//     stage(k+2) outstanding.
//   - LDS 16B-granule XOR swizzle g' = g ^ (row&3) ^ ((row>>2)&3) applied to
//     the GLOBAL source (DMA dest stays linear, m104/m173) and to the ds_read
//     address -> 2-way conflict (free) instead of 8-way.
// Buffer selection is integer offset arithmetic (NOT a pointer array: an LDS
// pointer array trips "addrspacecast in static initializer" on gfx950).

__global__ __launch_bounds__(512, 4) void k_gemm1(const bf16* __restrict__ xb,
                                                  const bf16* __restrict__ w1t,
                                                  bf16* __restrict__ h1) {
    __shared__ bf16 As[3 * 128 * KBLK];  // 3 x 8 KB rotating buffers
    const int tid = threadIdx.x;
    const int wave = tid >> 6;
    const int lane = tid & 63;
    const int q = lane >> 4;
    const int r = lane & 15;
    const int row0 = blockIdx.x * 128;
    const int wrow0 = (wave & 1) * 64;
    const int wcol0 = (wave >> 1) * 64;

    // staging: thread t owns LDS 16B granule t (row t>>2, slot t&3); the slot
    // holds global granule g = slot ^ (row&3) ^ ((row>>2)&3) (pre-swizzled src)
    const int sg = (tid & 3) ^ ((tid >> 2) & 3) ^ ((tid >> 4) & 3);
    int gsrow = row0 + (tid >> 2);
    if (gsrow >= NN) gsrow = NN - 1;  // clamp; C-stores guarded
    const bf16* gsrc = xb + (size_t)gsrow * KP1 + sg * 8;

    // A-frag LDS element offsets (fixed per thread): row R, want granule q ->
    // stored at slot q ^ (R&3) ^ ((R>>2)&3)
    int aoff[4];
#pragma unroll
    for (int rt = 0; rt < 4; ++rt) {
        int R = wrow0 + rt * 16 + r;
        int gq = q ^ (R & 3) ^ ((R >> 2) & 3);
        aoff[rt] = R * KBLK + gq * 8;
    }

    const bf16* brow[4];
#pragma unroll
    for (int ct = 0; ct < 4; ++ct)
        brow[ct] = w1t + (size_t)(wcol0 + ct * 16 + r) * KP1 + q * 8;

    f32x4 acc[4][4];
#pragma unroll
    for (int a = 0; a < 4; ++a)
#pragma unroll
        for (int b = 0; b < 4; ++b) acc[a][b] = (f32x4){0.f, 0.f, 0.f, 0.f};

    auto stage = [&](int bi, int kk) {
        const bf16* g = gsrc + kk * KBLK;
        bf16* l = As + bi * (128 * KBLK) + tid * 8;  // wave-uniform base + lane*16B
        __builtin_amdgcn_global_load_lds(
            (const __attribute__((address_space(1))) unsigned int*)g,
            (__attribute__((address_space(3))) unsigned int*)l, 16, 0, 0);
    };

    stage(0, 0);
    stage(1, 1);
    asm volatile("s_waitcnt vmcnt(1)" ::: "memory");  // buf0 resident, s1 in flight
    __builtin_amdgcn_s_barrier();

    int cur = 0, nx2 = 2;
#pragma unroll 1
    for (int kk = 0; kk < 19; ++kk) {
        const int k0 = kk * KBLK;
        // B loads FIRST (oldest non-stage vmem this phase)
        union { uint4 u; bf16x8 v; } ub[4];
#pragma unroll
        for (int ct = 0; ct < 4; ++ct) ub[ct].u = *(const uint4*)(brow[ct] + k0);
        // deep prefetch: stage k+2 (retired 2 phases from now)
        if (kk + 2 < 19) stage(nx2, kk + 2);
        // A fragments from the resident buffer
        const bf16* bufk = As + cur * (128 * KBLK);
        bf16x8 af[4];
#pragma unroll
        for (int rt = 0; rt < 4; ++rt) {
            union { uint4 u; bf16x8 v; } ua;
            ua.u = *(const uint4*)(bufk + aoff[rt]);
            af[rt] = ua.v;
        }
#pragma unroll
        for (int ct = 0; ct < 4; ++ct)
#pragma unroll
            for (int rt = 0; rt < 4; ++rt)
                acc[rt][ct] = __builtin_amdgcn_mfma_f32_16x16x32_bf16(af[rt], ub[ct].v, acc[rt][ct], 0, 0, 0);
        // retire stage(k+1) (keep stage(k+2) outstanding); then barrier
        if (kk + 2 < 19) asm volatile("s_waitcnt vmcnt(1)" ::: "memory");
        else             asm volatile("s_waitcnt vmcnt(0)" ::: "memory");
        __builtin_amdgcn_s_barrier();
        cur = (cur == 2) ? 0 : cur + 1;
        nx2 = (nx2 == 2) ? 0 : nx2 + 1;
    }

#pragma unroll
    for (int rt = 0; rt < 4; ++rt) {
#pragma unroll
        for (int ct = 0; ct < 4; ++ct) {
            const int col = wcol0 + ct * 16 + r;
#pragma unroll
            for (int rr = 0; rr < 4; ++rr) {
                const int m = row0 + wrow0 + rt * 16 + q * 4 + rr;
                if (m < NN) h1[(size_t)m * H + col] = f2b(acc[rt][ct][rr]);
            }
        }
    }
}

// ---------------- layer-1 pull aggregation + bias + relu (fused) ----------------

__global__ __launch_bounds__(64) void k_gather1(const int* __restrict__ rowptr,
                                                const int* __restrict__ esrc,
                                                const bf16* __restrict__ h1,
                                                const float* __restrict__ dinv,
                                                const float* __restrict__ b1,
                                                bf16* __restrict__ hb) {
    const int n = blockIdx.x;
    const int tid = threadIdx.x;
    const float dn = dinv[n];

    uint2 u = ((const uint2*)(h1 + (size_t)n * H))[tid];
    float ws = dn * dn;
    float a0 = us2f((unsigned short)(u.x & 0xffff)) * ws;
    float a1 = us2f((unsigned short)(u.x >> 16)) * ws;
    float a2 = us2f((unsigned short)(u.y & 0xffff)) * ws;
    float a3 = us2f((unsigned short)(u.y >> 16)) * ws;

    const int beg = rowptr[n], end = rowptr[n + 1];
    int j = beg;
    for (; j + 3 < end; j += 4) {
        int s0 = esrc[j], s1 = esrc[j + 1], s2 = esrc[j + 2], s3 = esrc[j + 3];
        float w0 = dinv[s0] * dn, w1 = dinv[s1] * dn, w2 = dinv[s2] * dn, w3 = dinv[s3] * dn;
        uint2 v0 = ((const uint2*)(h1 + (size_t)s0 * H))[tid];
        uint2 v1 = ((const uint2*)(h1 + (size_t)s1 * H))[tid];
        uint2 v2 = ((const uint2*)(h1 + (size_t)s2 * H))[tid];
        uint2 v3 = ((const uint2*)(h1 + (size_t)s3 * H))[tid];
        a0 += us2f((unsigned short)(v0.x & 0xffff)) * w0;
        a1 += us2f((unsigned short)(v0.x >> 16)) * w0;
        a2 += us2f((unsigned short)(v0.y & 0xffff)) * w0;
        a3 += us2f((unsigned short)(v0.y >> 16)) * w0;
        a0 += us2f((unsigned short)(v1.x & 0xffff)) * w1;
        a1 += us2f((unsigned short)(v1.x >> 16)) * w1;
        a2 += us2f((unsigned short)(v1.y & 0xffff)) * w1;
        a3 += us2f((unsigned short)(v1.y >> 16)) * w1;
        a0 += us2f((unsigned short)(v2.x & 0xffff)) * w2;
        a1 += us2f((unsigned short)(v2.x >> 16)) * w2;
        a2 += us2f((unsigned short)(v2.y & 0xffff)) * w2;
        a3 += us2f((unsigned short)(v2.y >> 16)) * w2;
        a0 += us2f((unsigned short)(v3.x & 0xffff)) * w3;
        a1 += us2f((unsigned short)(v3.x >> 16)) * w3;
        a2 += us2f((unsigned short)(v3.y & 0xffff)) * w3;
        a3 += us2f((unsigned short)(v3.y >> 16)) * w3;
    }
    for (; j < end; ++j) {
        int s = esrc[j];
        float w = dinv[s] * dn;
        uint2 v = ((const uint2*)(h1 + (size_t)s * H))[tid];
        a0 += us2f((unsigned short)(v.x & 0xffff)) * w;
        a1 += us2f((unsigned short)(v.x >> 16)) * w;
        a2 += us2f((unsigned short)(v.y & 0xffff)) * w;
        a3 += us2f((unsigned short)(v.y >> 16)) * w;
    }

    float4 bb = ((const float4*)b1)[tid];
    a0 += bb.x; a1 += bb.y; a2 += bb.z; a3 += bb.w;
    a0 = a0 > 0.f ? a0 : 0.f;
    a1 = a1 > 0.f ? a1 : 0.f;
    a2 = a2 > 0.f ? a2 : 0.f;
    a3 = a3 > 0.f ? a3 : 0.f;

    union { unsigned short s[4]; uint2 u; } pk;
    union { bf16 b; unsigned short s; } cv;
    cv.b = f2b(a0); pk.s[0] = cv.s;
    cv.b = f2b(a1); pk.s[1] = cv.s;
    cv.b = f2b(a2); pk.s[2] = cv.s;
    cv.b = f2b(a3); pk.s[3] = cv.s;
    ((uint2*)(hb + (size_t)n * H))[tid] = pk.u;
}

// ---------------- GEMM2: h2[NN][42] = hb[NN][256] @ W2 ----------------
// Barrier-free direct-load design (waves own disjoint rows; B L2-hot).

__global__ __launch_bounds__(256) void k_gemm2(const bf16* __restrict__ hb,
                                               const bf16* __restrict__ w2t,
                                               bf16* __restrict__ h2) {
    const int tid = threadIdx.x;
    const int wave = tid >> 6;
    const int lane = tid & 63;
    const int q = lane >> 4;
    const int r = lane & 15;
    const int row0 = blockIdx.x * 128 + wave * 32;

    const bf16* arow[2];
#pragma unroll
    for (int rt = 0; rt < 2; ++rt) {
        int m = row0 + rt * 16 + r;
        if (m >= NN) m = NN - 1;
        arow[rt] = hb + (size_t)m * H + q * 8;
    }
    const bf16* brow[3];
#pragma unroll
    for (int ct = 0; ct < 3; ++ct)
        brow[ct] = w2t + (size_t)(ct * 16 + r) * H + q * 8;

    f32x4 acc[2][3];
#pragma unroll
    for (int a = 0; a < 2; ++a)
#pragma unroll
        for (int c = 0; c < 3; ++c) acc[a][c] = (f32x4){0.f, 0.f, 0.f, 0.f};

#pragma unroll 2
    for (int kk = 0; kk < 8; ++kk) {
        const int k0 = kk * 32;
        bf16x8 af[2];
#pragma unroll
        for (int rt = 0; rt < 2; ++rt) {
            union { uint4 u; bf16x8 v; } ua;
            ua.u = *(const uint4*)(arow[rt] + k0);
            af[rt] = ua.v;
        }
#pragma unroll
        for (int ct = 0; ct < 3; ++ct) {
            union { uint4 u; bf16x8 v; } ub;
            ub.u = *(const uint4*)(brow[ct] + k0);
#pragma unroll
            for (int rt = 0; rt < 2; ++rt)
                acc[rt][ct] = __builtin_amdgcn_mfma_f32_16x16x32_bf16(af[rt], ub.v, acc[rt][ct], 0, 0, 0);
        }
    }

#pragma unroll
    for (int rt = 0; rt < 2; ++rt) {
#pragma unroll
        for (int ct = 0; ct < 3; ++ct) {
            const int col = ct * 16 + r;
            if (col < C) {
#pragma unroll
                for (int rr = 0; rr < 4; ++rr) {
                    const int m = row0 + rt * 16 + q * 4 + rr;
                    if (m < NN) h2[(size_t)m * C + col] = f2b(acc[rt][ct][rr]);
                }
            }
        }
    }
}

// ---------------- layer-2 pull aggregation + bias + log_softmax (fused) ----------------

__global__ __launch_bounds__(64) void k_gather2(const int* __restrict__ rowptr,
                                                const int* __restrict__ esrc,
                                                const bf16* __restrict__ h2,
                                                const float* __restrict__ dinv,
                                                const float* __restrict__ b2,
                                                float* __restrict__ out) {
    const int n = blockIdx.x;
    const int c = threadIdx.x;
    const float dn = dinv[n];

    float acc = 0.f;
    if (c < C) acc = b2f(h2[(size_t)n * C + c]) * dn * dn;

    const int beg = rowptr[n], end = rowptr[n + 1];
    int j = beg;
    for (; j + 3 < end; j += 4) {
        int s0 = esrc[j], s1 = esrc[j + 1], s2 = esrc[j + 2], s3 = esrc[j + 3];
        float w0 = dinv[s0] * dn, w1 = dinv[s1] * dn, w2 = dinv[s2] * dn, w3 = dinv[s3] * dn;
        if (c < C) {
            float v0 = b2f(h2[(size_t)s0 * C + c]);
            float v1 = b2f(h2[(size_t)s1 * C + c]);
            float v2 = b2f(h2[(size_t)s2 * C + c]);
            float v3 = b2f(h2[(size_t)s3 * C + c]);
            acc += v0 * w0 + v1 * w1 + v2 * w2 + v3 * w3;
        }
    }
    for (; j < end; ++j) {
        int s = esrc[j];
        float w = dinv[s] * dn;
        if (c < C) acc += b2f(h2[(size_t)s * C + c]) * w;
    }

    float v = (c < C) ? acc + b2[c] : -INFINITY;
    float m = v;
#pragma unroll
    for (int o = 32; o > 0; o >>= 1) m = fmaxf(m, __shfl_xor(m, o, 64));
    float ex = (c < C) ? expf(v - m) : 0.f;
    float s = ex;
#pragma unroll
    for (int o = 32; o > 0; o >>= 1) s += __shfl_xor(s, o, 64);
    if (c < C) out[(size_t)n * C + c] = (v - m) - logf(s);
}

// ---------------- launch ----------------

extern "C" void kernel_launch(void* const* d_in, const int* in_sizes, int n_in,
                              void* d_out, int out_size, void* d_ws, size_t ws_size,
                              hipStream_t stream) {
    const float* x  = (const float*)d_in[0];  // fp32 [NN][602]
    const int*   ei = (const int*)d_in[1];    // int32 [2][NE]
    const float* w1 = (const float*)d_in[2];  // fp32 [602][256]
    const float* b1 = (const float*)d_in[3];  // fp32 [256]
    const float* w2 = (const float*)d_in[4];  // fp32 [256][42]
    const float* b2 = (const float*)d_in[5];  // fp32 [42]
    float* out = (float*)d_out;               // fp32 [NN][42]

    const int* src = ei;
    const int* dst = ei + NE;

    char* base = (char*)d_ws;
    size_t off = 0;
    auto alloc = [&](size_t bytes) -> void* {
        void* p = base + off;
        off += (bytes + 255) & ~(size_t)255;
        return p;
    };
    int*   cnt    = (int*)alloc((size_t)NN * 4);
    float* dinv   = (float*)alloc((size_t)NN * 4);
    int*   excl   = (int*)alloc((size_t)NN * 4);
    int*   bsum   = (int*)alloc(128 * 4);
    int*   rowptr = (int*)alloc((size_t)(NN + 1) * 4);
    int*   cursor = (int*)alloc((size_t)NN * 4);
    int*   esrc   = (int*)alloc((size_t)NE * 4);
    bf16*  w1t    = (bf16*)alloc((size_t)H * KP1 * 2);
    bf16*  w2t    = (bf16*)alloc((size_t)NP2 * H * 2);
    bf16*  h1     = (bf16*)alloc((size_t)NN * H * 2);
    bf16*  xb     = (bf16*)alloc((size_t)NN * KP1 * 2);  // 121.6 MB
    // xb is dead after k_gemm1; hb and h2 alias into it (sequential stream ->
    // gather1 writes hb only after gemm1's last xb read).
    bf16*  hb     = xb;                    // [NN][H]   (51.2 MB)
    bf16*  h2     = xb + (size_t)NN * H;   // [NN][C]   (8.4 MB), disjoint from hb
    (void)ws_size;

    // CSR build + norm
    k_zero<<<dim3((NN + 255) / 256), dim3(256), 0, stream>>>(cnt, NN);
    k_count<<<dim3((NE + 255) / 256), dim3(256), 0, stream>>>(dst, cnt);
    k_dinv<<<dim3((NN + 255) / 256), dim3(256), 0, stream>>>(cnt, dinv);
    k_scan1<<<dim3(NB1), dim3(256), 0, stream>>>(cnt, excl, bsum);
    k_scan2<<<dim3(1), dim3(128), 0, stream>>>(bsum);
    k_scan3<<<dim3(NB1), dim3(256), 0, stream>>>(excl, bsum, rowptr, cursor);
    k_fill<<<dim3((NE + 255) / 256), dim3(256), 0, stream>>>(src, dst, cursor, esrc);

    // weights
    k_transpose_w1<<<dim3(KP1), dim3(256), 0, stream>>>(w1, w1t);
    k_transpose_w2<<<dim3(NP2), dim3(256), 0, stream>>>(w2, w2t);

    // layer 1: stream-convert x, then DMA-pipelined bf16 GEMM
    k_convert<<<dim3((NCH + 255) / 256), dim3(256), 0, stream>>>(x, xb);
    k_gemm1<<<dim3((NN + 127) / 128), dim3(512), 0, stream>>>(xb, w1t, h1);
    k_gather1<<<dim3(NN), dim3(64), 0, stream>>>(rowptr, esrc, h1, dinv, b1, hb);

    // layer 2
    k_gemm2<<<dim3((NN + 127) / 128), dim3(256), 0, stream>>>(hb, w2t, h2);
    k_gather2<<<dim3(NN), dim3(64), 0, stream>>>(rowptr, esrc, h2, dinv, b2, out);
}